// Round 8
// baseline (256.245 us; speedup 1.0000x reference)
//
#include <hip/hip_runtime.h>
#include <hip/hip_cooperative_groups.h>
#include <hip/hip_bf16.h>

namespace cg = cooperative_groups;

typedef __attribute__((ext_vector_type(8))) short short8;   // 8 bf16 (MFMA A/B frag)
typedef __attribute__((ext_vector_type(4))) float floatx4;  // MFMA C/D frag
typedef unsigned int u32;

#define D_DIM 256
#define TCOLS 32
#define TILES 8       // cols per gemm sub-problem = 256
#define IDX_BITS 0x1FFFu      // 13-bit index payload (N=M=8192)
#define VAL_MASK 0xFFFFE000u  // truncated value bits (sim+2 positive -> raw bits monotone)

// ---------- helpers ----------

__device__ inline unsigned short f2bf_rne(float f) {
  u32 u = __float_as_uint(f);
  u32 r = (u + 0x7FFFu + ((u >> 16) & 1u)) >> 16;
  return (unsigned short)r;
}

__device__ inline u32 umax(u32 a, u32 b) { return a > b ? a : b; }

// ============================================================================
// FUSED cooperative kernel. Rationale: 8 rounds show the gemm is pinned at
// ~52us (2 waves/SIMD structural optimum: reg-alloc ~180 total incl AGPR;
// capping regs = spill catastrophe R1/R4; shrinking per-wave work = same
// period R6; LDS>=64KB kills co-scheduling R7). But best TOTAL is 104-114us:
// ~50-60us is small-kernel dur + ~15us/launch dispatch gaps. Fusing the
// 3 launches into one cooperative kernel attacks that directly.
// Grid 512 x 256: exactly 2 blocks/CU (LDS 33KB, regs ~180 -> capacity >=2).
//   phase 1: both transposes (b = bx[0,256) x fy{0,1}) + best-array init
//   grid.sync()
//   phase 2: R5's verified 52us gemm loop; block b -> x = shared rows,
//            two y sub-problems (y0, y0+16); af loaded ONCE per block;
//            XCD-chunked y0 (b%8) for B L2-locality; direct global col
//            atomics (R0/R7-verified), no in-loop barriers.
//   grid.sync()
//   phase 3: finalize on first 32 blocks.
// ============================================================================
__global__ __launch_bounds__(256, 2) void fused_all(const float* __restrict__ d0,
                                                    const float* __restrict__ d1,
                                                    unsigned short* __restrict__ At,
                                                    unsigned short* __restrict__ Bt2,
                                                    u32* __restrict__ best01,
                                                    u32* __restrict__ best10,
                                                    float* __restrict__ out,
                                                    int N, int M) {
  __shared__ alignas(16) unsigned short tile[64 * 132];  // 33 KB (phase 1 only)
  const int tid = threadIdx.x;
  const int b = blockIdx.x;

  // ---------------- phase 1: transpose-cast both inputs ----------------
  {
    const int bx = b & 255;   // 256 col-group units
    const int fy = b >> 8;    // feature half 0/1
    const int nblkA = N / 64;
    const bool isA = bx < nblkA;
    const float* src = isA ? d0 : d1;
    const int C = isA ? N : M;
    const int gd0 = (isA ? bx : bx - nblkA) * 64;
    const int d = tid & 63;
#pragma unroll
    for (int k = 0; k < 32; ++k) {
      int fl = (tid >> 6) + 4 * k;  // 0..127 within the half
      float v = src[(size_t)(fy * 128 + fl) * C + gd0 + d];
      tile[d * 132 + fl] = f2bf_rne(v);
    }
    __syncthreads();
    if (isA) {  // row-major At[row][256]
#pragma unroll
      for (int c = 0; c < 4; ++c) {
        int slot = c * 256 + tid;
        int dd = slot >> 4, f8 = slot & 15;
        short8 o = *(const short8*)(tile + dd * 132 + f8 * 8);
        *(short8*)(At + (size_t)(gd0 + dd) * D_DIM + fy * 128 + f8 * 8) = o;
      }
    } else {  // fragment-ordered Bt2 (see transpose_cast2 below for the map)
#pragma unroll
      for (int c = 0; c < 4; ++c) {
        int slot = c * 256 + tid;
        int dd = slot & 63;
        int f8l = c * 4 + (tid >> 6);
        int f8g = fy * 16 + f8l;
        short8 o = *(const short8*)(tile + dd * 132 + f8l * 8);
        size_t off = (size_t)((gd0 + dd) >> 5) * 8192 + (size_t)(f8g >> 2) * 1024 +
                     (size_t)((dd >> 4) & 1) * 512 + (f8g & 3) * 128 + (dd & 15) * 8;
        *(short8*)(Bt2 + off) = o;
      }
    }
    if (fy == 0) {  // best01/best10 contiguous: one init sweep
      int i = bx * 256 + tid;
      if (i < N + M) best01[i] = 0u;
    }
  }

  cg::this_grid().sync();

  // ---------------- phase 2: gemm + fused argmax (R5 structure) ----------------
  {
    const int wave = tid >> 6;
    const int lane = tid & 63;
    const int quad = lane >> 4;
    const int l15  = lane & 15;

    const int xcd = b & 7, kk = b >> 3;     // XCD-chunked: y-stripes per XCD
    const int x  = kk & 31;                 // N/256 == 32 row-blocks
    const int y0 = 2 * xcd + (kk >> 5);     // [0,16); second sub-problem y0+16
    const int n0 = x * 256;
    const int rbase = n0 + wave * 64;       // 64 rows per wave

    // A fragments once per block (shared by both y sub-problems): 128 VGPR
    short8 af[4][8];
#pragma unroll
    for (int t = 0; t < 4; ++t) {
      const unsigned short* ap = At + (size_t)(rbase + t * 16 + l15) * D_DIM + quad * 8;
#pragma unroll
      for (int kc = 0; kc < 8; ++kc)
        af[t][kc] = *(const short8*)(ap + kc * 32);
    }

    u32 rbk[16];
#pragma unroll
    for (int s = 0; s < 16; ++s) rbk[s] = 0u;
    const u32 rp0 = 0x1FFFu - (u32)(rbase + quad * 4);  // rowpay(i,r) = rp0-16i-r

#pragma unroll
    for (int yy = 0; yy < 2; ++yy) {
      const int mg0 = (y0 + yy * 16) * (TILES * TCOLS);
      const unsigned short* bp = Bt2 + (size_t)(mg0 >> 5) * 8192 + (size_t)lane * 8;
      for (int mt = 0; mt < TILES; ++mt) {
        const unsigned short* bpt = bp + (size_t)mt * 8192;
        floatx4 acc[4][2];
#pragma unroll
        for (int i = 0; i < 4; ++i)
#pragma unroll
          for (int j = 0; j < 2; ++j)
            acc[i][j] = (floatx4){2.0f, 2.0f, 2.0f, 2.0f};  // sim+2 > 0 bias
#pragma unroll
        for (int kc = 0; kc < 8; ++kc) {
          short8 bf0 = *(const short8*)(bpt + (kc * 2 + 0) * 512);
          short8 bf1 = *(const short8*)(bpt + (kc * 2 + 1) * 512);
          acc[0][0] = __builtin_amdgcn_mfma_f32_16x16x32_bf16(af[0][kc], bf0, acc[0][0], 0, 0, 0);
          acc[1][0] = __builtin_amdgcn_mfma_f32_16x16x32_bf16(af[1][kc], bf0, acc[1][0], 0, 0, 0);
          acc[2][0] = __builtin_amdgcn_mfma_f32_16x16x32_bf16(af[2][kc], bf0, acc[2][0], 0, 0, 0);
          acc[3][0] = __builtin_amdgcn_mfma_f32_16x16x32_bf16(af[3][kc], bf0, acc[3][0], 0, 0, 0);
          acc[0][1] = __builtin_amdgcn_mfma_f32_16x16x32_bf16(af[0][kc], bf1, acc[0][1], 0, 0, 0);
          acc[1][1] = __builtin_amdgcn_mfma_f32_16x16x32_bf16(af[1][kc], bf1, acc[1][1], 0, 0, 0);
          acc[2][1] = __builtin_amdgcn_mfma_f32_16x16x32_bf16(af[2][kc], bf1, acc[2][1], 0, 0, 0);
          acc[3][1] = __builtin_amdgcn_mfma_f32_16x16x32_bf16(af[3][kc], bf1, acc[3][1], 0, 0, 0);
        }
        // epilogue. C/D map: col = j*16 + l15, row = i*16 + quad*4 + r
        const int m0 = mg0 + mt * TCOLS;
        u32 cb[2] = {0u, 0u};
        u32 colpay[2] = {0x1FFFu - (u32)(m0 + l15), 0x1FFFu - (u32)(m0 + 16 + l15)};
#pragma unroll
        for (int i = 0; i < 4; ++i)
#pragma unroll
          for (int r = 0; r < 4; ++r) {
            u32 rp = rp0 - (u32)(i * 16 + r);
            u32 rb = rbk[i * 4 + r];
#pragma unroll
            for (int j = 0; j < 2; ++j) {
              u32 u = __float_as_uint(acc[i][j][r]) & VAL_MASK;
              rb = umax(rb, u | colpay[j]);
              cb[j] = umax(cb[j], u | rp);
            }
            rbk[i * 4 + r] = rb;
          }
        // col-argmax: quad butterfly + direct global atomic (fire-and-forget)
#pragma unroll
        for (int j = 0; j < 2; ++j) {
          u32 bb = cb[j];
          bb = umax(bb, (u32)__shfl_xor((int)bb, 16, 64));
          bb = umax(bb, (u32)__shfl_xor((int)bb, 32, 64));
          if (quad == 0) atomicMax(&best10[m0 + j * 16 + l15], bb);
        }
      }
    }
    // row flush: l15 butterfly, one atomic per row
#pragma unroll
    for (int i = 0; i < 4; ++i)
#pragma unroll
      for (int r = 0; r < 4; ++r) {
        u32 bb = rbk[i * 4 + r];
        bb = umax(bb, (u32)__shfl_xor((int)bb, 1, 64));
        bb = umax(bb, (u32)__shfl_xor((int)bb, 2, 64));
        bb = umax(bb, (u32)__shfl_xor((int)bb, 4, 64));
        bb = umax(bb, (u32)__shfl_xor((int)bb, 8, 64));
        if (l15 == 0) atomicMax(&best01[rbase + i * 16 + quad * 4 + r], bb);
      }
  }

  cg::this_grid().sync();

  // ---------------- phase 3: finalize ----------------
  if (b < (N >> 8)) {
    int n = b * 256 + tid;
    u32 k = best01[n];
    int idx01 = (int)((~k) & IDX_BITS);
    float sim = __uint_as_float(k & VAL_MASK) - 2.0f;
    int idx10 = (int)((~best10[idx01]) & IDX_BITS);
    float dist = 2.0f - 2.0f * sim;
    bool ok = (idx10 == n) && (dist <= 0.64f);
    out[n]     = ok ? (float)idx01 : -1.0f;
    out[N + n] = ok ? 1.5f - sim : 0.0f;
  }
}

// ============================================================================
// Fallback path (verified R5 kernels) — used if cooperative launch is
// unavailable or dims != 8192.
// ============================================================================

__global__ __launch_bounds__(256) void transpose_cast2(const float* __restrict__ d0,
                                                       const float* __restrict__ d1,
                                                       unsigned short* __restrict__ At,
                                                       unsigned short* __restrict__ Bt2,
                                                       int N, int M,
                                                       u32* __restrict__ best, int init_n) {
  __shared__ alignas(16) unsigned short tile[64 * 132];
  const int tid = threadIdx.x;
  const int bx = blockIdx.x;
  const int nblkA = N / 64;  // pass N=0 to do B only
  const bool isA = bx < nblkA;
  const float* src = isA ? d0 : d1;
  const int C = isA ? N : M;
  const int gd0 = (isA ? bx : bx - nblkA) * 64;
  const int d = tid & 63;
  const int fy = blockIdx.y;
#pragma unroll
  for (int k = 0; k < 32; ++k) {
    int fl = (tid >> 6) + 4 * k;
    float v = src[(size_t)(fy * 128 + fl) * C + gd0 + d];
    tile[d * 132 + fl] = f2bf_rne(v);
  }
  __syncthreads();
  if (isA) {
#pragma unroll
    for (int c = 0; c < 4; ++c) {
      int slot = c * 256 + tid;
      int dd = slot >> 4, f8 = slot & 15;
      short8 o = *(const short8*)(tile + dd * 132 + f8 * 8);
      *(short8*)(At + (size_t)(gd0 + dd) * D_DIM + fy * 128 + f8 * 8) = o;
    }
  } else {
#pragma unroll
    for (int c = 0; c < 4; ++c) {
      int slot = c * 256 + tid;
      int dd = slot & 63;
      int f8l = c * 4 + (tid >> 6);
      int f8g = fy * 16 + f8l;
      short8 o = *(const short8*)(tile + dd * 132 + f8l * 8);
      size_t off = (size_t)((gd0 + dd) >> 5) * 8192 + (size_t)(f8g >> 2) * 1024 +
                   (size_t)((dd >> 4) & 1) * 512 + (f8g & 3) * 128 + (dd & 15) * 8;
      *(short8*)(Bt2 + off) = o;
    }
  }
  if (fy == 0) {
    int i = bx * 256 + tid;
    if (i < init_n) best[i] = 0u;
  }
}

template <bool PRECAST>
__global__ __launch_bounds__(256) void gemm_reduce(const float* __restrict__ A,
                                                   const unsigned short* __restrict__ At,
                                                   const unsigned short* __restrict__ Bt2,
                                                   u32* __restrict__ best01,
                                                   u32* __restrict__ best10,
                                                   int N, int M) {
  const int tid  = threadIdx.x;
  const int wave = tid >> 6;
  const int lane = tid & 63;
  const int quad = lane >> 4;
  const int l15  = lane & 15;

  const int xB = N >> 8, yB = M >> 8;
  const int bid = blockIdx.x;
  int x, y;
  if ((yB & 7) == 0) {
    int c = bid & 7, k = bid >> 3;
    x = k % xB;
    y = c * (yB >> 3) + k / xB;
  } else {
    x = bid % xB;
    y = bid / xB;
  }
  const int n0  = x * 256;
  const int mg0 = y * (TILES * TCOLS);
  const int rbase = n0 + wave * 64;

  short8 af[4][8];
  if constexpr (PRECAST) {
#pragma unroll
    for (int t = 0; t < 4; ++t) {
      const unsigned short* ap = At + (size_t)(rbase + t * 16 + l15) * D_DIM + quad * 8;
#pragma unroll
      for (int kc = 0; kc < 8; ++kc)
        af[t][kc] = *(const short8*)(ap + kc * 32);
    }
  } else {
#pragma unroll
    for (int t = 0; t < 4; ++t)
#pragma unroll
      for (int kc = 0; kc < 8; ++kc) {
        const int row = rbase + t * 16 + l15;
        const int kb = kc * 32 + quad * 8;
        short8 o;
#pragma unroll
        for (int u = 0; u < 8; ++u)
          o[u] = (short)f2bf_rne(A[(size_t)(kb + u) * N + row]);
        af[t][kc] = o;
      }
  }

  const unsigned short* bp = Bt2 + (size_t)(mg0 >> 5) * 8192 + (size_t)lane * 8;

  u32 rbk[16];
#pragma unroll
  for (int s = 0; s < 16; ++s) rbk[s] = 0u;
  const u32 rp0 = 0x1FFFu - (u32)(rbase + quad * 4);

  for (int mt = 0; mt < TILES; ++mt) {
    const unsigned short* bpt = bp + (size_t)mt * 8192;
    floatx4 acc[4][2];
#pragma unroll
    for (int i = 0; i < 4; ++i)
#pragma unroll
      for (int j = 0; j < 2; ++j)
        acc[i][j] = (floatx4){2.0f, 2.0f, 2.0f, 2.0f};
#pragma unroll
    for (int kc = 0; kc < 8; ++kc) {
      short8 bf0 = *(const short8*)(bpt + (kc * 2 + 0) * 512);
      short8 bf1 = *(const short8*)(bpt + (kc * 2 + 1) * 512);
      acc[0][0] = __builtin_amdgcn_mfma_f32_16x16x32_bf16(af[0][kc], bf0, acc[0][0], 0, 0, 0);
      acc[1][0] = __builtin_amdgcn_mfma_f32_16x16x32_bf16(af[1][kc], bf0, acc[1][0], 0, 0, 0);
      acc[2][0] = __builtin_amdgcn_mfma_f32_16x16x32_bf16(af[2][kc], bf0, acc[2][0], 0, 0, 0);
      acc[3][0] = __builtin_amdgcn_mfma_f32_16x16x32_bf16(af[3][kc], bf0, acc[3][0], 0, 0, 0);
      acc[0][1] = __builtin_amdgcn_mfma_f32_16x16x32_bf16(af[0][kc], bf1, acc[0][1], 0, 0, 0);
      acc[1][1] = __builtin_amdgcn_mfma_f32_16x16x32_bf16(af[1][kc], bf1, acc[1][1], 0, 0, 0);
      acc[2][1] = __builtin_amdgcn_mfma_f32_16x16x32_bf16(af[2][kc], bf1, acc[2][1], 0, 0, 0);
      acc[3][1] = __builtin_amdgcn_mfma_f32_16x16x32_bf16(af[3][kc], bf1, acc[3][1], 0, 0, 0);
    }
    const int m0 = mg0 + mt * TCOLS;
    u32 cb[2] = {0u, 0u};
    u32 colpay[2] = {0x1FFFu - (u32)(m0 + l15), 0x1FFFu - (u32)(m0 + 16 + l15)};
#pragma unroll
    for (int i = 0; i < 4; ++i)
#pragma unroll
      for (int r = 0; r < 4; ++r) {
        u32 rp = rp0 - (u32)(i * 16 + r);
        u32 rb = rbk[i * 4 + r];
#pragma unroll
        for (int j = 0; j < 2; ++j) {
          u32 u = __float_as_uint(acc[i][j][r]) & VAL_MASK;
          rb = umax(rb, u | colpay[j]);
          cb[j] = umax(cb[j], u | rp);
        }
        rbk[i * 4 + r] = rb;
      }
#pragma unroll
    for (int j = 0; j < 2; ++j) {
      u32 bb = cb[j];
      bb = umax(bb, (u32)__shfl_xor((int)bb, 16, 64));
      bb = umax(bb, (u32)__shfl_xor((int)bb, 32, 64));
      if (quad == 0) atomicMax(&best10[m0 + j * 16 + l15], bb);
    }
  }
#pragma unroll
  for (int i = 0; i < 4; ++i)
#pragma unroll
    for (int r = 0; r < 4; ++r) {
      u32 bb = rbk[i * 4 + r];
      bb = umax(bb, (u32)__shfl_xor((int)bb, 1, 64));
      bb = umax(bb, (u32)__shfl_xor((int)bb, 2, 64));
      bb = umax(bb, (u32)__shfl_xor((int)bb, 4, 64));
      bb = umax(bb, (u32)__shfl_xor((int)bb, 8, 64));
      if (l15 == 0) atomicMax(&best01[rbase + i * 16 + quad * 4 + r], bb);
    }
}

__global__ void finalize(const u32* __restrict__ best01, const u32* __restrict__ best10,
                         float* __restrict__ out, int N) {
  int n = blockIdx.x * blockDim.x + threadIdx.x;
  if (n >= N) return;
  u32 k = best01[n];
  int idx01 = (int)((~k) & IDX_BITS);
  float sim = __uint_as_float(k & VAL_MASK) - 2.0f;
  int idx10 = (int)((~best10[idx01]) & IDX_BITS);
  float dist = 2.0f - 2.0f * sim;
  bool ok = (idx10 == n) && (dist <= 0.64f);
  out[n]     = ok ? (float)idx01 : -1.0f;
  out[N + n] = ok ? 1.5f - sim : 0.0f;
}

// ---------- launcher ----------

extern "C" void kernel_launch(void* const* d_in, const int* in_sizes, int n_in,
                              void* d_out, int out_size, void* d_ws, size_t ws_size,
                              hipStream_t stream) {
  (void)n_in; (void)out_size;
  const float* d0 = (const float*)d_in[0];  // [256][N]
  const float* d1 = (const float*)d_in[1];  // [256][M]
  const int N = in_sizes[0] / D_DIM;        // 8192
  const int M = in_sizes[1] / D_DIM;        // 8192

  u32* best01 = (u32*)d_ws;                            // N u32
  u32* best10 = best01 + N;                            // M u32
  unsigned short* At  = (unsigned short*)(best10 + M); // [N][256] bf16
  unsigned short* Bt2 = At + (size_t)N * D_DIM;        // frag-ordered bf16
  float* out = (float*)d_out;

  const size_t need = (size_t)(N + M) * sizeof(u32) +
                      (size_t)(N + M) * D_DIM * sizeof(unsigned short);

  if (N == 8192 && M == 8192 && ws_size >= need) {
    void* args[] = {(void*)&d0, (void*)&d1, (void*)&At, (void*)&Bt2,
                    (void*)&best01, (void*)&best10, (void*)&out,
                    (void*)&N, (void*)&M};
    hipError_t e = hipLaunchCooperativeKernel((void*)fused_all, dim3(512), dim3(256),
                                              args, 0, stream);
    if (e == hipSuccess) return;
    // else fall through to the 3-launch path
  }

  if (ws_size >= need) {
    hipLaunchKernelGGL(transpose_cast2, dim3((N + M) / 64, 2), dim3(256), 0, stream,
                       d0, d1, At, Bt2, N, M, best01, N + M);
    hipLaunchKernelGGL((gemm_reduce<true>), dim3((N / 256) * (M / 256)), dim3(256), 0,
                       stream, d0, At, Bt2, best01, best10, N, M);
  } else {
    unsigned short* BtF = (unsigned short*)(best10 + M);
    hipLaunchKernelGGL(transpose_cast2, dim3(M / 64, 2), dim3(256), 0, stream,
                       d1, d1, BtF, BtF, 0, M, best01, N + M);
    hipLaunchKernelGGL((gemm_reduce<false>), dim3((N / 256) * (M / 256)), dim3(256), 0,
                       stream, d0, BtF, BtF, best01, best10, N, M);
  }
  hipLaunchKernelGGL(finalize, dim3(N / 256), dim3(256), 0, stream, best01, best10, out, N);
}